// Round 10
// baseline (1175.233 us; speedup 1.0000x reference)
//
#include <hip/hip_runtime.h>
#include <hip/hip_fp16.h>

#define N_NODES 30000
#define N_EDGES 240000
#define EMB     300
#define NPAD    30080   // 235*128, 940*32
#define K1      320     // padded EMB (gemm1 K, agg cols, fp16)
#define NP1     640     // padded 2*EMB (MLP hidden)
#define NP2     384     // h2 padded col count / row stride
#define HSH     304     // h row stride in fp16 elements
#define MROWS   32      // rows per fused-MLP block
#define SPA     344     // A LDS row stride: dword-stride 172 == 12 (mod 32) -> 2-way free
#define SP      664     // P LDS row stride: dword-stride 332 == 12 (mod 32) -> 2-way free
#define LAYERS  5

typedef _Float16 half8 __attribute__((ext_vector_type(8)));
typedef __attribute__((ext_vector_type(4))) float floatx4;

// ---------------- weight conversion / transpose (fp16) ----------------
__global__ void conv_w1t_kernel(const float* __restrict__ W1, __half* __restrict__ w1t) {
  int idx = blockIdx.x * 256 + threadIdx.x;
  if (idx >= LAYERS * NP1 * K1) return;
  int l = idx / (NP1 * K1);
  int rem = idx % (NP1 * K1);
  int n = rem / K1, k = rem % K1;
  float v = (n < 2 * EMB && k < EMB) ? W1[(size_t)l * EMB * 2 * EMB + (size_t)k * 2 * EMB + n] : 0.f;
  w1t[idx] = __float2half(v);
}
__global__ void conv_w2t_kernel(const float* __restrict__ W2, __half* __restrict__ w2t) {
  int idx = blockIdx.x * 256 + threadIdx.x;
  if (idx >= LAYERS * NP2 * NP1) return;
  int l = idx / (NP2 * NP1);
  int rem = idx % (NP2 * NP1);
  int n = rem / NP1, k = rem % NP1;
  float v = (n < EMB && k < 2 * EMB) ? W2[(size_t)l * 2 * EMB * EMB + (size_t)k * EMB + n] : 0.f;
  w2t[idx] = __float2half(v);
}
// both bias pads in one dispatch
__global__ void conv_bias_kernel(const float* __restrict__ b1, const float* __restrict__ b2,
                                 float* __restrict__ b1p, float* __restrict__ b2p) {
  int idx = blockIdx.x * 256 + threadIdx.x;
  if (idx < LAYERS * NP1) {
    int l = idx / NP1, j = idx % NP1;
    b1p[idx] = (j < 2 * EMB) ? b1[l * 2 * EMB + j] : 0.f;
  } else {
    idx -= LAYERS * NP1;
    if (idx < LAYERS * NP2) {
      int l = idx / NP2, j = idx % NP2;
      b2p[idx] = (j < EMB) ? b2[l * EMB + j] : 0.f;
    }
  }
}

// ---------------- initial embedding (fp16 h) ----------------
__global__ __launch_bounds__(256)
void embed_kernel(const int* __restrict__ x, const float* __restrict__ emb1,
                  const float* __restrict__ emb2, __half* __restrict__ h) {
  int node = blockIdx.x;
  int t0 = x[node * 2], t1 = x[node * 2 + 1];
  for (int c = threadIdx.x; c < EMB; c += 256)
    h[(size_t)node * HSH + c] = __float2half(emb1[t0 * EMB + c] + emb2[t1 * EMB + c]);
}

// ---------------- CSR build ----------------
__global__ void count_kernel(const int* __restrict__ ei, int* __restrict__ deg) {
  int e = blockIdx.x * 256 + threadIdx.x;
  if (e < N_EDGES) atomicAdd(&deg[ei[N_EDGES + e]], 1);
}

// fast scan: thread-chunked serial + wave shuffle scan + 16-wave LDS scan.
#define SCH 30   // 1024 * 30 = 30720 >= N_NODES
__global__ __launch_bounds__(1024)
void scan_kernel(const int* __restrict__ deg, int* __restrict__ row_ptr,
                 int* __restrict__ curs) {
  int tid = threadIdx.x;
  int base = tid * SCH;
  int loc[SCH];
  int s = 0;
#pragma unroll
  for (int j = 0; j < SCH; ++j) {
    int i = base + j;
    int v = (i < N_NODES) ? deg[i] : 0;
    loc[j] = s;          // exclusive prefix within chunk
    s += v;
  }
  int lane = tid & 63, wv = tid >> 6;
  int x = s;
#pragma unroll
  for (int o = 1; o < 64; o <<= 1) {
    int y = __shfl_up(x, o, 64);
    if (lane >= o) x += y;
  }
  __shared__ int wsum[16], woff[16];
  if (lane == 63) wsum[wv] = x;
  __syncthreads();
  if (tid == 0) {
    int acc = 0;
    for (int w = 0; w < 16; ++w) { woff[w] = acc; acc += wsum[w]; }
    row_ptr[N_NODES] = acc;
  }
  __syncthreads();
  int excl = woff[wv] + x - s;    // exclusive prefix of this thread's chunk
#pragma unroll
  for (int j = 0; j < SCH; ++j) {
    int i = base + j;
    if (i < N_NODES) { int val = excl + loc[j]; row_ptr[i] = val; curs[i] = val; }
  }
}

__global__ void fill_kernel(const int* __restrict__ ei, const int* __restrict__ ea,
                            int* __restrict__ cursor, int* __restrict__ ebuf) {
  int e = blockIdx.x * 256 + threadIdx.x;
  if (e >= N_EDGES) return;
  int d = ei[N_EDGES + e];
  int pos = atomicAdd(&cursor[d], 1);
  ebuf[pos] = ei[e] * 32 + (ea[2 * e] * 3 + ea[2 * e + 1]);  // src*32 + combo
}

// ---------------- aggregation: fp16 gather-sum, 2x edge unroll (proven 50.4us) ----------------
__global__ __launch_bounds__(256)
void aggregate_kernel(const __half* __restrict__ h,
                      const int* __restrict__ row_ptr,
                      const int* __restrict__ ebuf,
                      const float* __restrict__ e1,   // [6,300] this layer
                      const float* __restrict__ e2,   // [3,300] this layer
                      __half* __restrict__ agg) {
  __shared__ __half2 combo[18][150];
  int tid = threadIdx.x;
  for (int idx = tid; idx < 18 * 150; idx += 256) {
    int t = idx / 150, p = idx % 150;
    int a0 = t / 3, a1 = t % 3;
    combo[t][p] = __floats2half2_rn(e1[a0 * EMB + 2 * p]     + e2[a1 * EMB + 2 * p],
                                    e1[a0 * EMB + 2 * p + 1] + e2[a1 * EMB + 2 * p + 1]);
  }
  __syncthreads();
  int wave = tid >> 6, lane = tid & 63;
  int node = blockIdx.x * 4 + wave;
  float a0x = 0.f, a0y = 0.f, a1x = 0.f, a1y = 0.f, a2x = 0.f, a2y = 0.f;
  float b0x = 0.f, b0y = 0.f, b1x = 0.f, b1y = 0.f, b2x = 0.f, b2y = 0.f;
  int p2 = lane + 128;
  bool has2 = (p2 < 150);
  if (node < N_NODES) {
    int ebeg = row_ptr[node], eend = row_ptr[node + 1];
    int e = ebeg;
    for (; e + 2 <= eend; e += 2) {
      int v0 = ebuf[e], v1 = ebuf[e + 1];
      int s0 = v0 >> 5, t0 = v0 & 31;
      int s1 = v1 >> 5, t1 = v1 & 31;
      const __half2* hp0 = (const __half2*)(h + (size_t)s0 * HSH);
      const __half2* hp1 = (const __half2*)(h + (size_t)s1 * HSH);
      float2 u00 = __half22float2(hp0[lane]);
      float2 u01 = __half22float2(hp0[lane + 64]);
      float2 u10 = __half22float2(hp1[lane]);
      float2 u11 = __half22float2(hp1[lane + 64]);
      float2 c00 = __half22float2(combo[t0][lane]);
      float2 c01 = __half22float2(combo[t0][lane + 64]);
      float2 c10 = __half22float2(combo[t1][lane]);
      float2 c11 = __half22float2(combo[t1][lane + 64]);
      a0x += u00.x + c00.x;  a0y += u00.y + c00.y;
      a1x += u01.x + c01.x;  a1y += u01.y + c01.y;
      b0x += u10.x + c10.x;  b0y += u10.y + c10.y;
      b1x += u11.x + c11.x;  b1y += u11.y + c11.y;
      if (has2) {
        float2 u02 = __half22float2(hp0[p2]);
        float2 u12 = __half22float2(hp1[p2]);
        float2 c02 = __half22float2(combo[t0][p2]);
        float2 c12 = __half22float2(combo[t1][p2]);
        a2x += u02.x + c02.x;  a2y += u02.y + c02.y;
        b2x += u12.x + c12.x;  b2y += u12.y + c12.y;
      }
    }
    for (; e <= eend; ++e) {   // tail edge (if odd count) + self loop
      int s, t;
      if (e < eend) { int v = ebuf[e]; s = v >> 5; t = v & 31; }
      else          { s = node;        t = 4 * 3 + 0; }
      const __half2* hp = (const __half2*)(h + (size_t)s * HSH);
      float2 u0 = __half22float2(hp[lane]);
      float2 u1 = __half22float2(hp[lane + 64]);
      float2 c0 = __half22float2(combo[t][lane]);
      float2 c1 = __half22float2(combo[t][lane + 64]);
      a0x += u0.x + c0.x;  a0y += u0.y + c0.y;
      a1x += u1.x + c1.x;  a1y += u1.y + c1.y;
      if (has2) {
        float2 u2 = __half22float2(hp[p2]);
        float2 c2 = __half22float2(combo[t][p2]);
        a2x += u2.x + c2.x;  a2y += u2.y + c2.y;
      }
    }
  }
  a0x += b0x; a0y += b0y; a1x += b1x; a1y += b1y; a2x += b2x; a2y += b2y;
  __half2* op = (__half2*)(agg + (size_t)node * K1);
  op[lane]      = __floats2half2_rn(a0x, a0y);
  op[lane + 64] = __floats2half2_rn(a1x, a1y);
  if (p2 < 160) op[p2] = has2 ? __floats2half2_rn(a2x, a2y)
                              : __floats2half2_rn(0.f, 0.f);   // zero K-pad cols
}

// ---------------- fused MLP: h2 = A@W1t(+b1,relu) @ W2t (+b2), stats fused ----------------
// Block = 512 threads (8 waves), owns MROWS=32 rows, covers ALL cols.
// v2: A staged ONCE (barrier-free K-loops), conflict-free LDS strides (== 12 mod 32 dwords),
// 3 barriers total (vs 20). B fragments direct from L2-hot global, pipelined by compiler.
// NOTE: A (aggb) and h2 MUST NOT alias — blocks read/write concurrently.
__global__ __launch_bounds__(512, 4)
void mlp_kernel(const __half* __restrict__ A,
                const __half* __restrict__ w1t,
                const __half* __restrict__ w2t,
                const float* __restrict__ b1p,
                const float* __restrict__ b2p,
                __half* __restrict__ h2,
                float* __restrict__ stats) {
  __shared__ _Float16 As[MROWS * SPA];  // 22.0 KB, whole A tile
  __shared__ _Float16 P[MROWS * SP];    // 42.5 KB
  __shared__ float cs[NP2], cq[NP2];    // 3 KB
  int tid = threadIdx.x;
  int wave = tid >> 6, lane = tid & 63;
  int l15 = lane & 15, q = lane >> 4;
  int row0 = blockIdx.x * MROWS;

  if (tid < NP2) { cs[tid] = 0.f; cq[tid] = 0.f; }

  // stage whole A tile: 32 rows x 40 16B-chunks = 1280 chunks, 512 threads
  for (int idx = tid; idx < MROWS * (K1 / 8); idx += 512) {
    int r = idx / (K1 / 8), c = idx % (K1 / 8);
    *(uint4*)&As[r * SPA + c * 8] = *(const uint4*)&A[(size_t)(row0 + r) * K1 + c * 8];
  }
  __syncthreads();   // barrier 1 (also covers cs/cq init)

  floatx4 zero4 = {0.f, 0.f, 0.f, 0.f};
  // ---- phase 1: P = relu(A @ W1t + b1), wave owns 80-col strip (5 N-tiles), NO barriers ----
  floatx4 acc1[2][5];
#pragma unroll
  for (int i = 0; i < 2; ++i)
#pragma unroll
    for (int j = 0; j < 5; ++j) acc1[i][j] = zero4;

  for (int kc = 0; kc < K1; kc += 32) {
    half8 af0 = *(const half8*)&As[l15 * SPA + kc + q * 8];
    half8 af1 = *(const half8*)&As[(16 + l15) * SPA + kc + q * 8];
#pragma unroll
    for (int nt = 0; nt < 5; ++nt) {
      half8 bf = *(const half8*)&w1t[(size_t)(wave * 80 + nt * 16 + l15) * K1 + kc + q * 8];
      acc1[0][nt] = __builtin_amdgcn_mfma_f32_16x16x32_f16(af0, bf, acc1[0][nt], 0, 0, 0);
      acc1[1][nt] = __builtin_amdgcn_mfma_f32_16x16x32_f16(af1, bf, acc1[1][nt], 0, 0, 0);
    }
  }
  // bias + relu -> P (C/D layout: col=lane&15, row=quad*4+r)
#pragma unroll
  for (int mi = 0; mi < 2; ++mi)
#pragma unroll
    for (int nt = 0; nt < 5; ++nt) {
      int col = wave * 80 + nt * 16 + l15;
      float bv = b1p[col];
#pragma unroll
      for (int r = 0; r < 4; ++r) {
        int pr = mi * 16 + q * 4 + r;
        P[pr * SP + col] = (_Float16)fmaxf(acc1[mi][nt][r] + bv, 0.f);
      }
    }
  __syncthreads();   // barrier 2: P complete

  // ---- phase 2: h2 = P @ W2t + b2, wave owns 48-col strip (3 N-tiles), NO barriers ----
  floatx4 acc2[2][3];
#pragma unroll
  for (int i = 0; i < 2; ++i)
#pragma unroll
    for (int j = 0; j < 3; ++j) acc2[i][j] = zero4;
  for (int kc = 0; kc < NP1; kc += 32) {
    half8 af0 = *(const half8*)&P[l15 * SP + kc + q * 8];
    half8 af1 = *(const half8*)&P[(16 + l15) * SP + kc + q * 8];
#pragma unroll
    for (int nt = 0; nt < 3; ++nt) {
      half8 bf = *(const half8*)&w2t[(size_t)(wave * 48 + nt * 16 + l15) * NP1 + kc + q * 8];
      acc2[0][nt] = __builtin_amdgcn_mfma_f32_16x16x32_f16(af0, bf, acc2[0][nt], 0, 0, 0);
      acc2[1][nt] = __builtin_amdgcn_mfma_f32_16x16x32_f16(af1, bf, acc2[1][nt], 0, 0, 0);
    }
  }
  // epilogue: bias, store, BN stats
  float ls[3] = {0.f, 0.f, 0.f}, lq2[3] = {0.f, 0.f, 0.f};
#pragma unroll
  for (int mi = 0; mi < 2; ++mi)
#pragma unroll
    for (int nt = 0; nt < 3; ++nt) {
      int col = wave * 48 + nt * 16 + l15;
      float bv = b2p[col];
#pragma unroll
      for (int r = 0; r < 4; ++r) {
        int row = row0 + mi * 16 + q * 4 + r;
        float v = acc2[mi][nt][r] + bv;
        h2[(size_t)row * NP2 + col] = __float2half(v);
        if (row < N_NODES) { ls[nt] += v; lq2[nt] += v * v; }
      }
    }
#pragma unroll
  for (int nt = 0; nt < 3; ++nt) {
    int col = wave * 48 + nt * 16 + l15;
    atomicAdd(&cs[col], ls[nt]);
    atomicAdd(&cq[col], lq2[nt]);
  }
  __syncthreads();   // barrier 3: stats complete
  if (tid < EMB) {
    atomicAdd(&stats[tid], cs[tid]);
    atomicAdd(&stats[EMB + tid], cq[tid]);
  }
}

// ---------------- batchnorm apply (+relu), half2 vectorized ----------------
__global__ __launch_bounds__(192)
void bn_kernel(const __half* __restrict__ h2, const float* __restrict__ stats,
               const float* __restrict__ gamma, const float* __restrict__ beta,
               __half* __restrict__ hout, float* __restrict__ fout, int relu) {
  int node = blockIdx.x;
  int c2 = threadIdx.x;          // half2 index, 150 active
  if (c2 >= 150) return;
  const float invN = 1.0f / (float)N_NODES;
  int c0 = 2 * c2, c1 = 2 * c2 + 1;
  float mean0 = stats[c0] * invN, mean1 = stats[c1] * invN;
  float var0 = stats[EMB + c0] * invN - mean0 * mean0;
  float var1 = stats[EMB + c1] * invN - mean1 * mean1;
  float sc0 = gamma[c0] * rsqrtf(var0 + 1e-5f);
  float sc1 = gamma[c1] * rsqrtf(var1 + 1e-5f);
  float sh0 = beta[c0] - mean0 * sc0;
  float sh1 = beta[c1] - mean1 * sc1;
  float2 hv = __half22float2(((const __half2*)(h2 + (size_t)node * NP2))[c2]);
  float v0 = hv.x * sc0 + sh0;
  float v1 = hv.y * sc1 + sh1;
  if (relu) { v0 = fmaxf(v0, 0.f); v1 = fmaxf(v1, 0.f); }
  if (hout) {
    ((__half2*)(hout + (size_t)node * HSH))[c2] = __floats2half2_rn(v0, v1);
  } else {
    float2 o; o.x = v0; o.y = v1;
    *(float2*)(fout + (size_t)node * EMB + c0) = o;
  }
}

extern "C" void kernel_launch(void* const* d_in, const int* in_sizes, int n_in,
                              void* d_out, int out_size, void* d_ws, size_t ws_size,
                              hipStream_t stream) {
  const int*   x      = (const int*)d_in[0];
  const int*   ei     = (const int*)d_in[1];
  const int*   ea     = (const int*)d_in[2];
  const float* x_emb1 = (const float*)d_in[3];
  const float* x_emb2 = (const float*)d_in[4];
  const float* edge1  = (const float*)d_in[5];
  const float* edge2  = (const float*)d_in[6];
  const float* W1     = (const float*)d_in[7];
  const float* b1     = (const float*)d_in[8];
  const float* W2     = (const float*)d_in[9];
  const float* b2     = (const float*)d_in[10];
  const float* gamma  = (const float*)d_in[11];
  const float* beta   = (const float*)d_in[12];
  float* out = (float*)d_out;

  char* ws = (char*)d_ws;
  size_t off = 0;
  auto nxt = [&](size_t bytes) {
    void* p = ws + off;
    off += (bytes + 255) & ~(size_t)255;
    return p;
  };
  // All buffers disjoint — mlp reads aggb while writing h2 (no aliasing allowed).
  __half* hbuf = (__half*)nxt((size_t)N_NODES * HSH * 2);   // 18.2 MB
  __half* aggb = (__half*)nxt((size_t)NPAD * K1 * 2);       // 19.3 MB
  __half* h2   = (__half*)nxt((size_t)NPAD * NP2 * 2);      // 23.1 MB
  __half* w1t  = (__half*)nxt((size_t)LAYERS * NP1 * K1 * 2);
  __half* w2t  = (__half*)nxt((size_t)LAYERS * NP2 * NP1 * 2);
  float*  b1p  = (float*)nxt((size_t)LAYERS * NP1 * 4);
  float*  b2p  = (float*)nxt((size_t)LAYERS * NP2 * 4);
  float*  stat = (float*)nxt((size_t)LAYERS * 2 * EMB * 4);
  int*    deg  = (int*)nxt((size_t)N_NODES * 4);
  int*    rptr = (int*)nxt((size_t)(N_NODES + 1) * 4);
  int*    curs = (int*)nxt((size_t)N_NODES * 4);
  int*    ebuf = (int*)nxt((size_t)N_EDGES * 4);
  // total ~67 MB

  hipMemsetAsync(deg, 0, (size_t)N_NODES * 4, stream);
  hipMemsetAsync(stat, 0, (size_t)LAYERS * 2 * EMB * 4, stream);

  conv_w1t_kernel<<<(LAYERS * NP1 * K1 + 255) / 256, 256, 0, stream>>>(W1, w1t);
  conv_w2t_kernel<<<(LAYERS * NP2 * NP1 + 255) / 256, 256, 0, stream>>>(W2, w2t);
  conv_bias_kernel<<<(LAYERS * (NP1 + NP2) + 255) / 256, 256, 0, stream>>>(b1, b2, b1p, b2p);

  embed_kernel<<<N_NODES, 256, 0, stream>>>(x, x_emb1, x_emb2, hbuf);

  count_kernel<<<(N_EDGES + 255) / 256, 256, 0, stream>>>(ei, deg);
  scan_kernel<<<1, 1024, 0, stream>>>(deg, rptr, curs);
  fill_kernel<<<(N_EDGES + 255) / 256, 256, 0, stream>>>(ei, ea, curs, ebuf);

  for (int l = 0; l < LAYERS; ++l) {
    aggregate_kernel<<<NPAD / 4, 256, 0, stream>>>(
        hbuf, rptr, ebuf, edge1 + (size_t)l * 6 * EMB, edge2 + (size_t)l * 3 * EMB, aggb);
    mlp_kernel<<<NPAD / MROWS, 512, 0, stream>>>(
        aggb, w1t + (size_t)l * NP1 * K1, w2t + (size_t)l * NP2 * NP1,
        b1p + l * NP1, b2p + l * NP2, h2, stat + l * 2 * EMB);
    bn_kernel<<<N_NODES, 192, 0, stream>>>(
        h2, stat + l * 2 * EMB, gamma + l * EMB, beta + l * EMB,
        (l < LAYERS - 1) ? hbuf : (__half*)nullptr,
        (l < LAYERS - 1) ? (float*)nullptr : out,
        (l < LAYERS - 1) ? 1 : 0);
  }
}

// Round 11
// 1090.928 us; speedup vs baseline: 1.0773x; 1.0773x over previous
//
#include <hip/hip_runtime.h>
#include <hip/hip_fp16.h>

#define N_NODES 30000
#define N_EDGES 240000
#define EMB     300
#define NPAD    30080   // 235*128, 940*32
#define K1      320     // padded EMB (gemm1 K, agg cols, fp16)
#define NP1     640     // padded 2*EMB (MLP hidden)
#define NP2     384     // h2 padded col count / row stride
#define HSH     304     // h row stride in fp16 elements
#define MROWS   32      // rows per fused-MLP block
#define SPA     344     // A LDS row stride
#define SP      664     // P LDS row stride
#define LAYERS  5

typedef _Float16 half8 __attribute__((ext_vector_type(8)));
typedef __attribute__((ext_vector_type(4))) float floatx4;

// async 16B global->LDS (per-lane gptr, LDS dest = wave-uniform base + lane*16)
__device__ __forceinline__ void gload16(const void* g, void* l) {
  __builtin_amdgcn_global_load_lds(
      (const __attribute__((address_space(1))) unsigned int*)g,
      (__attribute__((address_space(3))) unsigned int*)l, 16, 0, 0);
}

// ---------------- weight conversion / transpose (fp16) ----------------
__global__ void conv_w1t_kernel(const float* __restrict__ W1, __half* __restrict__ w1t) {
  int idx = blockIdx.x * 256 + threadIdx.x;
  if (idx >= LAYERS * NP1 * K1) return;
  int l = idx / (NP1 * K1);
  int rem = idx % (NP1 * K1);
  int n = rem / K1, k = rem % K1;
  float v = (n < 2 * EMB && k < EMB) ? W1[(size_t)l * EMB * 2 * EMB + (size_t)k * 2 * EMB + n] : 0.f;
  w1t[idx] = __float2half(v);
}
__global__ void conv_w2t_kernel(const float* __restrict__ W2, __half* __restrict__ w2t) {
  int idx = blockIdx.x * 256 + threadIdx.x;
  if (idx >= LAYERS * NP2 * NP1) return;
  int l = idx / (NP2 * NP1);
  int rem = idx % (NP2 * NP1);
  int n = rem / NP1, k = rem % NP1;
  float v = (n < EMB && k < 2 * EMB) ? W2[(size_t)l * 2 * EMB * EMB + (size_t)k * EMB + n] : 0.f;
  w2t[idx] = __float2half(v);
}
// both bias pads in one dispatch
__global__ void conv_bias_kernel(const float* __restrict__ b1, const float* __restrict__ b2,
                                 float* __restrict__ b1p, float* __restrict__ b2p) {
  int idx = blockIdx.x * 256 + threadIdx.x;
  if (idx < LAYERS * NP1) {
    int l = idx / NP1, j = idx % NP1;
    b1p[idx] = (j < 2 * EMB) ? b1[l * 2 * EMB + j] : 0.f;
  } else {
    idx -= LAYERS * NP1;
    if (idx < LAYERS * NP2) {
      int l = idx / NP2, j = idx % NP2;
      b2p[idx] = (j < EMB) ? b2[l * EMB + j] : 0.f;
    }
  }
}

// ---------------- initial embedding (fp16 h) ----------------
__global__ __launch_bounds__(256)
void embed_kernel(const int* __restrict__ x, const float* __restrict__ emb1,
                  const float* __restrict__ emb2, __half* __restrict__ h) {
  int node = blockIdx.x;
  int t0 = x[node * 2], t1 = x[node * 2 + 1];
  for (int c = threadIdx.x; c < EMB; c += 256)
    h[(size_t)node * HSH + c] = __float2half(emb1[t0 * EMB + c] + emb2[t1 * EMB + c]);
}

// ---------------- CSR build ----------------
__global__ void count_kernel(const int* __restrict__ ei, int* __restrict__ deg) {
  int e = blockIdx.x * 256 + threadIdx.x;
  if (e < N_EDGES) atomicAdd(&deg[ei[N_EDGES + e]], 1);
}

// fast scan: thread-chunked serial + wave shuffle scan + 16-wave LDS scan.
#define SCH 30   // 1024 * 30 = 30720 >= N_NODES
__global__ __launch_bounds__(1024)
void scan_kernel(const int* __restrict__ deg, int* __restrict__ row_ptr,
                 int* __restrict__ curs) {
  int tid = threadIdx.x;
  int base = tid * SCH;
  int loc[SCH];
  int s = 0;
#pragma unroll
  for (int j = 0; j < SCH; ++j) {
    int i = base + j;
    int v = (i < N_NODES) ? deg[i] : 0;
    loc[j] = s;          // exclusive prefix within chunk
    s += v;
  }
  int lane = tid & 63, wv = tid >> 6;
  int x = s;
#pragma unroll
  for (int o = 1; o < 64; o <<= 1) {
    int y = __shfl_up(x, o, 64);
    if (lane >= o) x += y;
  }
  __shared__ int wsum[16], woff[16];
  if (lane == 63) wsum[wv] = x;
  __syncthreads();
  if (tid == 0) {
    int acc = 0;
    for (int w = 0; w < 16; ++w) { woff[w] = acc; acc += wsum[w]; }
    row_ptr[N_NODES] = acc;
  }
  __syncthreads();
  int excl = woff[wv] + x - s;    // exclusive prefix of this thread's chunk
#pragma unroll
  for (int j = 0; j < SCH; ++j) {
    int i = base + j;
    if (i < N_NODES) { int val = excl + loc[j]; row_ptr[i] = val; curs[i] = val; }
  }
}

__global__ void fill_kernel(const int* __restrict__ ei, const int* __restrict__ ea,
                            int* __restrict__ cursor, int* __restrict__ ebuf) {
  int e = blockIdx.x * 256 + threadIdx.x;
  if (e >= N_EDGES) return;
  int d = ei[N_EDGES + e];
  int pos = atomicAdd(&cursor[d], 1);
  ebuf[pos] = ei[e] * 32 + (ea[2 * e] * 3 + ea[2 * e + 1]);  // src*32 + combo
}

// ---------------- aggregation: fp16 gather-sum, 2x edge unroll (proven 50.4us) ----------------
__global__ __launch_bounds__(256)
void aggregate_kernel(const __half* __restrict__ h,
                      const int* __restrict__ row_ptr,
                      const int* __restrict__ ebuf,
                      const float* __restrict__ e1,   // [6,300] this layer
                      const float* __restrict__ e2,   // [3,300] this layer
                      __half* __restrict__ agg) {
  __shared__ __half2 combo[18][150];
  int tid = threadIdx.x;
  for (int idx = tid; idx < 18 * 150; idx += 256) {
    int t = idx / 150, p = idx % 150;
    int a0 = t / 3, a1 = t % 3;
    combo[t][p] = __floats2half2_rn(e1[a0 * EMB + 2 * p]     + e2[a1 * EMB + 2 * p],
                                    e1[a0 * EMB + 2 * p + 1] + e2[a1 * EMB + 2 * p + 1]);
  }
  __syncthreads();
  int wave = tid >> 6, lane = tid & 63;
  int node = blockIdx.x * 4 + wave;
  float a0x = 0.f, a0y = 0.f, a1x = 0.f, a1y = 0.f, a2x = 0.f, a2y = 0.f;
  float b0x = 0.f, b0y = 0.f, b1x = 0.f, b1y = 0.f, b2x = 0.f, b2y = 0.f;
  int p2 = lane + 128;
  bool has2 = (p2 < 150);
  if (node < N_NODES) {
    int ebeg = row_ptr[node], eend = row_ptr[node + 1];
    int e = ebeg;
    for (; e + 2 <= eend; e += 2) {
      int v0 = ebuf[e], v1 = ebuf[e + 1];
      int s0 = v0 >> 5, t0 = v0 & 31;
      int s1 = v1 >> 5, t1 = v1 & 31;
      const __half2* hp0 = (const __half2*)(h + (size_t)s0 * HSH);
      const __half2* hp1 = (const __half2*)(h + (size_t)s1 * HSH);
      float2 u00 = __half22float2(hp0[lane]);
      float2 u01 = __half22float2(hp0[lane + 64]);
      float2 u10 = __half22float2(hp1[lane]);
      float2 u11 = __half22float2(hp1[lane + 64]);
      float2 c00 = __half22float2(combo[t0][lane]);
      float2 c01 = __half22float2(combo[t0][lane + 64]);
      float2 c10 = __half22float2(combo[t1][lane]);
      float2 c11 = __half22float2(combo[t1][lane + 64]);
      a0x += u00.x + c00.x;  a0y += u00.y + c00.y;
      a1x += u01.x + c01.x;  a1y += u01.y + c01.y;
      b0x += u10.x + c10.x;  b0y += u10.y + c10.y;
      b1x += u11.x + c11.x;  b1y += u11.y + c11.y;
      if (has2) {
        float2 u02 = __half22float2(hp0[p2]);
        float2 u12 = __half22float2(hp1[p2]);
        float2 c02 = __half22float2(combo[t0][p2]);
        float2 c12 = __half22float2(combo[t1][p2]);
        a2x += u02.x + c02.x;  a2y += u02.y + c02.y;
        b2x += u12.x + c12.x;  b2y += u12.y + c12.y;
      }
    }
    for (; e <= eend; ++e) {   // tail edge (if odd count) + self loop
      int s, t;
      if (e < eend) { int v = ebuf[e]; s = v >> 5; t = v & 31; }
      else          { s = node;        t = 4 * 3 + 0; }
      const __half2* hp = (const __half2*)(h + (size_t)s * HSH);
      float2 u0 = __half22float2(hp[lane]);
      float2 u1 = __half22float2(hp[lane + 64]);
      float2 c0 = __half22float2(combo[t][lane]);
      float2 c1 = __half22float2(combo[t][lane + 64]);
      a0x += u0.x + c0.x;  a0y += u0.y + c0.y;
      a1x += u1.x + c1.x;  a1y += u1.y + c1.y;
      if (has2) {
        float2 u2 = __half22float2(hp[p2]);
        float2 c2 = __half22float2(combo[t][p2]);
        a2x += u2.x + c2.x;  a2y += u2.y + c2.y;
      }
    }
  }
  a0x += b0x; a0y += b0y; a1x += b1x; a1y += b1y; a2x += b2x; a2y += b2y;
  __half2* op = (__half2*)(agg + (size_t)node * K1);
  op[lane]      = __floats2half2_rn(a0x, a0y);
  op[lane + 64] = __floats2half2_rn(a1x, a1y);
  if (p2 < 160) op[p2] = has2 ? __floats2half2_rn(a2x, a2y)
                              : __floats2half2_rn(0.f, 0.f);   // zero K-pad cols
}

// ---------------- fused MLP v3: slab-staged B via global_load_lds ----------------
// Block = 512 threads (8 waves), MROWS=32 rows, all cols.
// Per K-step the block bulk-DMAs the FULL B-slab (640x32 / 384x32) into LDS —
// 2560 16B chunks in flight — then m97-style 2-barrier consume. Fixes R9/R10's
// per-wave register B-loads (MfmaUtil 7%: ~160 serialized L2 loads/wave).
// LDS 106 KB -> 1 block/CU; latency lives in the DMA queue, not wave count.
// NOTE: A (aggb) and h2 MUST NOT alias — blocks read/write concurrently.
__global__ __launch_bounds__(512, 1)
void mlp_kernel(const __half* __restrict__ A,
                const __half* __restrict__ w1t,
                const __half* __restrict__ w2t,
                const float* __restrict__ b1p,
                const float* __restrict__ b2p,
                __half* __restrict__ h2,
                float* __restrict__ stats) {
  __shared__ _Float16 As[MROWS * SPA];  // 22.0 KB, whole A tile
  __shared__ _Float16 P[MROWS * SP];    // 42.5 KB
  __shared__ _Float16 Bs[NP1 * 32];     // 40 KB slab (phase2 uses 24 KB subset)
  __shared__ float cs[NP2], cq[NP2];    // 3 KB
  int tid = threadIdx.x;
  int wave = tid >> 6, lane = tid & 63;
  int l15 = lane & 15, q = lane >> 4;
  int row0 = blockIdx.x * MROWS;

  if (tid < NP2) { cs[tid] = 0.f; cq[tid] = 0.f; }

  // stage whole A tile once: 32 rows x 40 16B-chunks
  for (int idx = tid; idx < MROWS * (K1 / 8); idx += 512) {
    int r = idx / (K1 / 8), c = idx % (K1 / 8);
    *(uint4*)&As[r * SPA + c * 8] = *(const uint4*)&A[(size_t)(row0 + r) * K1 + c * 8];
  }

  floatx4 zero4 = {0.f, 0.f, 0.f, 0.f};
  // ---- phase 1: P = relu(A @ W1t + b1), wave owns 80-col strip (5 N-tiles) ----
  floatx4 acc1[2][5];
#pragma unroll
  for (int i = 0; i < 2; ++i)
#pragma unroll
    for (int j = 0; j < 5; ++j) acc1[i][j] = zero4;

  // slab staging geometry: thread t covers rows (t>>2)+j*128, 16B chunk (t&3)*8;
  // LDS dest = Bs[t*8 + j*4096] halfs = wave-uniform base + lane*16 bytes  ✓
  int bn = tid >> 2, bc = (tid & 3) * 8;
  for (int kc = 0; kc < K1; kc += 32) {
    __syncthreads();   // prev slab consumed (iter0: also orders cs/cq init)
#pragma unroll
    for (int j = 0; j < 5; ++j)
      gload16(&w1t[(size_t)(bn + j * 128) * K1 + kc + bc], &Bs[(size_t)tid * 8 + j * 4096]);
    __syncthreads();   // drains vmcnt + lgkm: slab (and As on iter0) ready
    half8 af0 = *(const half8*)&As[l15 * SPA + kc + q * 8];
    half8 af1 = *(const half8*)&As[(16 + l15) * SPA + kc + q * 8];
#pragma unroll
    for (int nt = 0; nt < 5; ++nt) {
      half8 bf = *(const half8*)&Bs[(wave * 80 + nt * 16 + l15) * 32 + q * 8];
      acc1[0][nt] = __builtin_amdgcn_mfma_f32_16x16x32_f16(af0, bf, acc1[0][nt], 0, 0, 0);
      acc1[1][nt] = __builtin_amdgcn_mfma_f32_16x16x32_f16(af1, bf, acc1[1][nt], 0, 0, 0);
    }
  }
  // bias + relu -> P (C/D layout: col=lane&15, row=quad*4+r)
#pragma unroll
  for (int mi = 0; mi < 2; ++mi)
#pragma unroll
    for (int nt = 0; nt < 5; ++nt) {
      int col = wave * 80 + nt * 16 + l15;
      float bv = b1p[col];
#pragma unroll
      for (int r = 0; r < 4; ++r) {
        int pr = mi * 16 + q * 4 + r;
        P[pr * SP + col] = (_Float16)fmaxf(acc1[mi][nt][r] + bv, 0.f);
      }
    }

  // ---- phase 2: h2 = P @ W2t + b2, wave owns 48-col strip (3 N-tiles) ----
  floatx4 acc2[2][3];
#pragma unroll
  for (int i = 0; i < 2; ++i)
#pragma unroll
    for (int j = 0; j < 3; ++j) acc2[i][j] = zero4;
  for (int kc = 0; kc < NP1; kc += 32) {
    __syncthreads();   // P writes + prev slab reads complete
#pragma unroll
    for (int j = 0; j < 3; ++j)
      gload16(&w2t[(size_t)(bn + j * 128) * NP1 + kc + bc], &Bs[(size_t)tid * 8 + j * 4096]);
    __syncthreads();   // slab ready
    half8 af0 = *(const half8*)&P[l15 * SP + kc + q * 8];
    half8 af1 = *(const half8*)&P[(16 + l15) * SP + kc + q * 8];
#pragma unroll
    for (int nt = 0; nt < 3; ++nt) {
      half8 bf = *(const half8*)&Bs[(wave * 48 + nt * 16 + l15) * 32 + q * 8];
      acc2[0][nt] = __builtin_amdgcn_mfma_f32_16x16x32_f16(af0, bf, acc2[0][nt], 0, 0, 0);
      acc2[1][nt] = __builtin_amdgcn_mfma_f32_16x16x32_f16(af1, bf, acc2[1][nt], 0, 0, 0);
    }
  }
  // epilogue: bias, store, BN stats
  float ls[3] = {0.f, 0.f, 0.f}, lq2[3] = {0.f, 0.f, 0.f};
#pragma unroll
  for (int mi = 0; mi < 2; ++mi)
#pragma unroll
    for (int nt = 0; nt < 3; ++nt) {
      int col = wave * 48 + nt * 16 + l15;
      float bv = b2p[col];
#pragma unroll
      for (int r = 0; r < 4; ++r) {
        int row = row0 + mi * 16 + q * 4 + r;
        float v = acc2[mi][nt][r] + bv;
        h2[(size_t)row * NP2 + col] = __float2half(v);
        if (row < N_NODES) { ls[nt] += v; lq2[nt] += v * v; }
      }
    }
#pragma unroll
  for (int nt = 0; nt < 3; ++nt) {
    int col = wave * 48 + nt * 16 + l15;
    atomicAdd(&cs[col], ls[nt]);
    atomicAdd(&cq[col], lq2[nt]);
  }
  __syncthreads();
  if (tid < EMB) {
    atomicAdd(&stats[tid], cs[tid]);
    atomicAdd(&stats[EMB + tid], cq[tid]);
  }
}

// ---------------- batchnorm apply (+relu), half2 vectorized ----------------
__global__ __launch_bounds__(192)
void bn_kernel(const __half* __restrict__ h2, const float* __restrict__ stats,
               const float* __restrict__ gamma, const float* __restrict__ beta,
               __half* __restrict__ hout, float* __restrict__ fout, int relu) {
  int node = blockIdx.x;
  int c2 = threadIdx.x;          // half2 index, 150 active
  if (c2 >= 150) return;
  const float invN = 1.0f / (float)N_NODES;
  int c0 = 2 * c2, c1 = 2 * c2 + 1;
  float mean0 = stats[c0] * invN, mean1 = stats[c1] * invN;
  float var0 = stats[EMB + c0] * invN - mean0 * mean0;
  float var1 = stats[EMB + c1] * invN - mean1 * mean1;
  float sc0 = gamma[c0] * rsqrtf(var0 + 1e-5f);
  float sc1 = gamma[c1] * rsqrtf(var1 + 1e-5f);
  float sh0 = beta[c0] - mean0 * sc0;
  float sh1 = beta[c1] - mean1 * sc1;
  float2 hv = __half22float2(((const __half2*)(h2 + (size_t)node * NP2))[c2]);
  float v0 = hv.x * sc0 + sh0;
  float v1 = hv.y * sc1 + sh1;
  if (relu) { v0 = fmaxf(v0, 0.f); v1 = fmaxf(v1, 0.f); }
  if (hout) {
    ((__half2*)(hout + (size_t)node * HSH))[c2] = __floats2half2_rn(v0, v1);
  } else {
    float2 o; o.x = v0; o.y = v1;
    *(float2*)(fout + (size_t)node * EMB + c0) = o;
  }
}

extern "C" void kernel_launch(void* const* d_in, const int* in_sizes, int n_in,
                              void* d_out, int out_size, void* d_ws, size_t ws_size,
                              hipStream_t stream) {
  const int*   x      = (const int*)d_in[0];
  const int*   ei     = (const int*)d_in[1];
  const int*   ea     = (const int*)d_in[2];
  const float* x_emb1 = (const float*)d_in[3];
  const float* x_emb2 = (const float*)d_in[4];
  const float* edge1  = (const float*)d_in[5];
  const float* edge2  = (const float*)d_in[6];
  const float* W1     = (const float*)d_in[7];
  const float* b1     = (const float*)d_in[8];
  const float* W2     = (const float*)d_in[9];
  const float* b2     = (const float*)d_in[10];
  const float* gamma  = (const float*)d_in[11];
  const float* beta   = (const float*)d_in[12];
  float* out = (float*)d_out;

  char* ws = (char*)d_ws;
  size_t off = 0;
  auto nxt = [&](size_t bytes) {
    void* p = ws + off;
    off += (bytes + 255) & ~(size_t)255;
    return p;
  };
  // All buffers disjoint — mlp reads aggb while writing h2 (no aliasing allowed).
  __half* hbuf = (__half*)nxt((size_t)N_NODES * HSH * 2);   // 18.2 MB
  __half* aggb = (__half*)nxt((size_t)NPAD * K1 * 2);       // 19.3 MB
  __half* h2   = (__half*)nxt((size_t)NPAD * NP2 * 2);      // 23.1 MB
  __half* w1t  = (__half*)nxt((size_t)LAYERS * NP1 * K1 * 2);
  __half* w2t  = (__half*)nxt((size_t)LAYERS * NP2 * NP1 * 2);
  float*  b1p  = (float*)nxt((size_t)LAYERS * NP1 * 4);
  float*  b2p  = (float*)nxt((size_t)LAYERS * NP2 * 4);
  float*  stat = (float*)nxt((size_t)LAYERS * 2 * EMB * 4);
  int*    deg  = (int*)nxt((size_t)N_NODES * 4);
  int*    rptr = (int*)nxt((size_t)(N_NODES + 1) * 4);
  int*    curs = (int*)nxt((size_t)N_NODES * 4);
  int*    ebuf = (int*)nxt((size_t)N_EDGES * 4);
  // total ~67 MB

  hipMemsetAsync(deg, 0, (size_t)N_NODES * 4, stream);
  hipMemsetAsync(stat, 0, (size_t)LAYERS * 2 * EMB * 4, stream);

  conv_w1t_kernel<<<(LAYERS * NP1 * K1 + 255) / 256, 256, 0, stream>>>(W1, w1t);
  conv_w2t_kernel<<<(LAYERS * NP2 * NP1 + 255) / 256, 256, 0, stream>>>(W2, w2t);
  conv_bias_kernel<<<(LAYERS * (NP1 + NP2) + 255) / 256, 256, 0, stream>>>(b1, b2, b1p, b2p);

  embed_kernel<<<N_NODES, 256, 0, stream>>>(x, x_emb1, x_emb2, hbuf);

  count_kernel<<<(N_EDGES + 255) / 256, 256, 0, stream>>>(ei, deg);
  scan_kernel<<<1, 1024, 0, stream>>>(deg, rptr, curs);
  fill_kernel<<<(N_EDGES + 255) / 256, 256, 0, stream>>>(ei, ea, curs, ebuf);

  for (int l = 0; l < LAYERS; ++l) {
    aggregate_kernel<<<NPAD / 4, 256, 0, stream>>>(
        hbuf, rptr, ebuf, edge1 + (size_t)l * 6 * EMB, edge2 + (size_t)l * 3 * EMB, aggb);
    mlp_kernel<<<NPAD / MROWS, 512, 0, stream>>>(
        aggb, w1t + (size_t)l * NP1 * K1, w2t + (size_t)l * NP2 * NP1,
        b1p + l * NP1, b2p + l * NP2, h2, stat + l * 2 * EMB);
    bn_kernel<<<N_NODES, 192, 0, stream>>>(
        h2, stat + l * 2 * EMB, gamma + l * EMB, beta + l * EMB,
        (l < LAYERS - 1) ? hbuf : (__half*)nullptr,
        (l < LAYERS - 1) ? (float*)nullptr : out,
        (l < LAYERS - 1) ? 1 : 0);
  }
}